// Round 4
// baseline (265.274 us; speedup 1.0000x reference)
//
#include <hip/hip_runtime.h>
#include <math.h>

#define B_    4096
#define N_    10
#define DIN_  32
#define D_    128
#define PHI_  256
#define RHO_  128
#define L_    3
#define EPS_  1e-5f

// ---- fp16 helpers (bits in short) ----
__device__ __forceinline__ short f2hs(float f) {            // f32 -> fp16 RNE
    union { _Float16 h; short s; } u;
    u.h = (_Float16)f;
    return u.s;
}
__device__ __forceinline__ float hs2f(short s) {
    union { _Float16 h; short s; } u;
    u.s = s;
    return (float)u.h;
}

typedef short    s16x8 __attribute__((ext_vector_type(8)));
typedef _Float16 h16x8 __attribute__((ext_vector_type(8)));
typedef float    f32x4 __attribute__((ext_vector_type(4)));
typedef float    v2f   __attribute__((ext_vector_type(2)));

__device__ __forceinline__ h16x8 ld8h(const short* p) {
    union { s16x8 s; h16x8 h; } u;
    u.s = *(const s16x8*)p;
    return u.h;
}
__device__ __forceinline__ h16x8 cvt8(const float* p) {     // 8 f32 -> 8 fp16
    f32x4 x0 = *(const f32x4*)p;
    f32x4 x1 = *(const f32x4*)(p + 4);
    h16x8 a;
    a[0]=(_Float16)x0[0]; a[1]=(_Float16)x0[1]; a[2]=(_Float16)x0[2]; a[3]=(_Float16)x0[3];
    a[4]=(_Float16)x1[0]; a[5]=(_Float16)x1[1]; a[6]=(_Float16)x1[2]; a[7]=(_Float16)x1[3];
    return a;
}

__device__ __forceinline__ v2f splat2(float s) { v2f r; r.x = s; r.y = s; return r; }
__device__ __forceinline__ v2f fma2(v2f a, v2f b, v2f c) { return __builtin_elementwise_fma(a, b, c); }

// ---- d_ws layout (fp16 elements). Fragment unit = 64 lanes x 8 el = 512 el.
// For matrix W[K][N]: frag (nt,ks) at ((nt*KS+ks)*64+lane)*8, lane holds
// W[ks*32+(lane>>4)*8+j][nt*16+(lane&15)], j=0..7  (B-operand layout, 16x16x32)
#define WS_WE1 0
#define WS_WE2 4096
#define WS_RGW 20480
#define WS_RGR 118784
#define WS_L1  167936
#define WS_L2  217088
#define WS_P1  266240
#define WS_P2  299008
#define WS_R1  364544

// ================= prep kernel: fp32 weights -> fp16 B-fragments ==========
__global__ __launch_bounds__(64)
void prep_weights(const float* __restrict__ We1, const float* __restrict__ We2,
                  const float* __restrict__ rgw, const float* __restrict__ rgr,
                  const float* __restrict__ l1w, const float* __restrict__ l2w,
                  const float* __restrict__ p1w, const float* __restrict__ p2w,
                  const float* __restrict__ r1w, short* __restrict__ ws)
{
    int bi = blockIdx.x, l = threadIdx.x;
    const float* src; int KS, Nw, dstOff, tt;
    if      (bi <   8) { src = We1; KS = 1; Nw = 128; dstOff = WS_WE1; tt = bi; }
    else if (bi <  40) { src = We2; KS = 4; Nw = 128; dstOff = WS_WE2; tt = bi - 8; }
    else if (bi < 232) { int m = (bi - 40) >> 5;  src = rgw + m * 16384; KS = 4; Nw = 128; dstOff = WS_RGW + m * 16384; tt = (bi - 40)  & 31; }
    else if (bi < 328) { int m = (bi - 232) >> 5; src = rgr + m * 16384; KS = 4; Nw = 128; dstOff = WS_RGR + m * 16384; tt = (bi - 232) & 31; }
    else if (bi < 424) { int m = (bi - 328) >> 5; src = l1w + m * 16384; KS = 4; Nw = 128; dstOff = WS_L1  + m * 16384; tt = (bi - 328) & 31; }
    else if (bi < 520) { int m = (bi - 424) >> 5; src = l2w + m * 16384; KS = 4; Nw = 128; dstOff = WS_L2  + m * 16384; tt = (bi - 424) & 31; }
    else if (bi < 584) { src = p1w; KS = 4; Nw = 256; dstOff = WS_P1; tt = bi - 520; }
    else if (bi < 712) { src = p2w; KS = 8; Nw = 256; dstOff = WS_P2; tt = bi - 584; }
    else               { src = r1w; KS = 8; Nw = 128; dstOff = WS_R1; tt = bi - 712; }
    int nt = tt / KS, ks = tt - nt * KS;
    int kbase = ks * 32 + (l >> 4) * 8;
    int col   = nt * 16 + (l & 15);
    union { short s[8]; int4 v; } u;
#pragma unroll
    for (int j = 0; j < 8; ++j)
        u.s[j] = f2hs(src[(size_t)(kbase + j) * Nw + col]);
    *(int4*)(ws + dstOff + ((size_t)tt * 64 + l) * 8) = u.v;
}

// ================= main kernel: 1 block (4 waves) = 2 graphs ===============
// Each weight B-fragment is loaded ONCE per wave and used for 2 MFMAs (one
// per graph) -> L2 weight traffic halves vs 1 graph/block.
// A-operand layout: lane holds A[m=lane&15][k=(lane>>4)*8+j]; rows >=10 clamped
// C/D layout: col = lane&15, row = (lane>>4)*4 + reg

template<int NTP>
__device__ __forceinline__ void initC(f32x4* acc, const float* __restrict__ bias, int c16) {
#pragma unroll
    for (int j = 0; j < NTP; ++j) {
        float bv = bias[j * 16 + c16];
        acc[j] = (f32x4){bv, bv, bv, bv};
    }
}

#define MFMA16(a, b, c) __builtin_amdgcn_mfma_f32_16x16x32_f16(a, b, c, 0, 0, 0)

// dual-graph matmul, fp16 A from LDS
template<int KS, int NTP>
__device__ __forceinline__ void mm2_a16(const short* __restrict__ Wf,
                                        const short* __restrict__ A0, const short* __restrict__ A1,
                                        int ldA, int mrow, int q, int l,
                                        f32x4* acc0, f32x4* acc1) {
#pragma unroll
    for (int ks = 0; ks < KS; ++ks) {
        h16x8 a0 = ld8h(A0 + mrow * ldA + ks * 32 + q * 8);
        h16x8 a1 = ld8h(A1 + mrow * ldA + ks * 32 + q * 8);
#pragma unroll
        for (int j = 0; j < NTP; ++j) {
            h16x8 bv = ld8h(Wf + ((size_t)(j * KS + ks) * 64 + l) * 8);
            acc0[j] = MFMA16(a0, bv, acc0[j]);
            acc1[j] = MFMA16(a1, bv, acc1[j]);
        }
    }
}

// dual-graph matmul, fp32 A from LDS (converted per k-slice)
template<int KS, int NTP>
__device__ __forceinline__ void mm2_a32(const short* __restrict__ Wf,
                                        const float* __restrict__ A0, const float* __restrict__ A1,
                                        int ldA, int mrow, int q, int l,
                                        f32x4* acc0, f32x4* acc1) {
#pragma unroll
    for (int ks = 0; ks < KS; ++ks) {
        h16x8 a0 = cvt8(A0 + mrow * ldA + ks * 32 + q * 8);
        h16x8 a1 = cvt8(A1 + mrow * ldA + ks * 32 + q * 8);
#pragma unroll
        for (int j = 0; j < NTP; ++j) {
            h16x8 bv = ld8h(Wf + ((size_t)(j * KS + ks) * 64 + l) * 8);
            acc0[j] = MFMA16(a0, bv, acc0[j]);
            acc1[j] = MFMA16(a1, bv, acc1[j]);
        }
    }
}

// store C tiles as fp16 into LDS (row-major, ldD elements), rows >= 10 dropped.
template<int NTP, bool RELU>
__device__ __forceinline__ void storeC16(const f32x4* acc, short* __restrict__ dst,
                                         int ldD, int q, int c16) {
#pragma unroll
    for (int j = 0; j < NTP; ++j) {
#pragma unroll
        for (int i = 0; i < 4; ++i) {
            int r = q * 4 + i;
            if (r < 10) {
                float v = acc[j][i];
                if (RELU) v = fmaxf(v, 0.f);
                dst[r * ldD + j * 16 + c16] = f2hs(v);
            }
        }
    }
}

#define HLD 132   // Hf row stride (f32); %32 words = 4 -> worst 2-way (free)
#define SLD 392   // staging row stride (fp16); 784 B rows, 16B-aligned, 2-way max

__global__ __launch_bounds__(256, 4)
void gcn_main(const float* __restrict__ A, const float* __restrict__ X,
              const int* __restrict__ home_mask,
              const float* __restrict__ be1, const float* __restrict__ be2,
              const float* __restrict__ rgcn_b,
              const float* __restrict__ l1b, const float* __restrict__ l2b,
              const float* __restrict__ ln_g, const float* __restrict__ ln_b,
              const float* __restrict__ p1b, const float* __restrict__ p2b,
              const float* __restrict__ r1b, const float* __restrict__ r2w,
              const short* __restrict__ ws, float* __restrict__ out)
{
    const int b   = blockIdx.x;        // graph pair: graphs 2b, 2b+1
    const int tid = threadIdx.x;       // 0..255
    const int wv  = tid >> 6;          // wave 0..3 (owns nt = wv*NTP ..)
    const int l   = tid & 63;          // lane
    const int q   = l >> 4;
    const int c16 = l & 15;
    const int mrow = (c16 < 10) ? c16 : 9;

    // per-graph state (31.2 KB total -> 5 blocks/CU)
    __shared__ __align__(16) float HfS[2][N_ * HLD];   // residual H, fp32
    __shared__ __align__(16) short StS[2][N_ * SLD];   // staging: HW0|HW1|HWr / LN|hidden / phi
    __shared__ __align__(16) short RhoS[2][512];       // [hs ; aws] fp16
    __shared__ float AsS[2][100];                      // signed A
    __shared__ float C0S[2][100], C1S[2][100];         // |A|·D0·M0^T etc (layer-invariant)
    __shared__ float invc0S[2][N_], invc1S[2][N_], rsAS[2][N_];
    __shared__ float hmfS[2][16], awfS[2][16];
    __shared__ float dS[8];

    // ---- phase 0: stage A (signed) + masks + embed1 ----
    if (tid < 200) {
        int g = tid / 100, e = tid - g * 100;
        AsS[g][e] = A[(size_t)(2 * b + g) * 100 + e];
    }
    if (tid < 32) {
        int g = tid >> 4, idx = tid & 15;
        float hm = 0.f, aw = 0.f;
        if (idx < 10) { hm = (float)home_mask[(2 * b + g) * N_ + idx]; aw = 1.f - hm; }
        hmfS[g][idx] = hm; awfS[g][idx] = aw;
    }
    {   // embed1: H1 = relu(X@We1 + be1) -> St[g][0:128]; shared B-frags
        f32x4 acc0[2], acc1[2];
        initC<2>(acc0, be1 + wv * 32, c16);
        initC<2>(acc1, be1 + wv * 32, c16);
        h16x8 a0 = cvt8(X + (size_t)(2 * b + 0) * (N_ * DIN_) + mrow * DIN_ + q * 8);
        h16x8 a1 = cvt8(X + (size_t)(2 * b + 1) * (N_ * DIN_) + mrow * DIN_ + q * 8);
#pragma unroll
        for (int j = 0; j < 2; ++j) {
            h16x8 bv = ld8h(ws + WS_WE1 + ((size_t)(wv * 2 + j) * 64 + l) * 8);
            acc0[j] = MFMA16(a0, bv, acc0[j]);
            acc1[j] = MFMA16(a1, bv, acc1[j]);
        }
        storeC16<2, true>(acc0, StS[0] + wv * 32, SLD, q, c16);
        storeC16<2, true>(acc1, StS[1] + wv * 32, SLD, q, c16);
    }
    __syncthreads();

    // ---- phase 1: invc + rsA (VALU) + embed2 (MFMA) ----
    if (tid < 20) {
        int g = tid / 10, j = tid - g * 10;
        float c1 = 0.f;
#pragma unroll
        for (int i = 0; i < 10; ++i) c1 += (AsS[g][i * 10 + j] > 0.f) ? 1.f : 0.f;
        invc1S[g][j] = 1.f / fmaxf(c1, 1.f);
        invc0S[g][j] = 1.f / fmaxf(10.f - c1, 1.f);
        float r = 0.f;
#pragma unroll
        for (int k = 0; k < 10; ++k) r += fabsf(AsS[g][j * 10 + k]);
        rsAS[g][j] = r;
    }
    {   // embed2: H = H1@We2 + be2 -> Hf (fp32)
        f32x4 acc0[2], acc1[2];
        initC<2>(acc0, be2 + wv * 32, c16);
        initC<2>(acc1, be2 + wv * 32, c16);
        mm2_a16<4, 2>(ws + WS_WE2 + (size_t)wv * 4096, StS[0], StS[1], SLD, mrow, q, l, acc0, acc1);
#pragma unroll
        for (int j = 0; j < 2; ++j)
#pragma unroll
            for (int i = 0; i < 4; ++i) {
                int r = q * 4 + i;
                if (r < 10) {
                    HfS[0][r * HLD + wv * 32 + j * 16 + c16] = acc0[j][i];
                    HfS[1][r * HLD + wv * 32 + j * 16 + c16] = acc1[j][i];
                }
            }
    }
    __syncthreads();

    // ---- phase 2: coefficient matrices (layer-invariant):
    //   agg = |A|·H2, H2 = D0·M0^T·HW0 + D1·M1^T·HW1 + HWr + 1·b^T
    //   => agg[i] = sum_k C0[i,k]·HW0[k] + C1[i,k]·HW1[k] + |A[i,k]|·HWr[k] + rsA[i]·b
    //   C0[i,k] = sum_j |A[i,j]|·invc0[j]·M0[k,j]
    if (tid < 200) {
        int g = tid / 100, e = tid - g * 100;
        int i = e / 10, k = e - i * 10;
        const float* As = AsS[g];
        float c0 = 0.f, c1 = 0.f;
#pragma unroll
        for (int j = 0; j < 10; ++j) {
            float aij = fabsf(As[i * 10 + j]);
            if (As[k * 10 + j] > 0.f) c1 += aij * invc1S[g][j];
            else                      c0 += aij * invc0S[g][j];
        }
        C0S[g][e] = c0; C1S[g][e] = c1;
    }
    __syncthreads();

    const v2f lg2 = *(const v2f*)(ln_g + 2 * l);
    const v2f lb2 = *(const v2f*)(ln_b + 2 * l);

    // ---- layers ----
    for (int ll = 0; ll < L_; ++ll) {
        // fused RGCN matmuls: HW0|HW1|HWr -> St[g][0:384] (shared A-cvt, shared nothing else)
        {
            const short* W0f = ws + WS_RGW + (size_t)(ll * 2 + 0) * 16384 + (size_t)wv * 4096;
            const short* W1f = ws + WS_RGW + (size_t)(ll * 2 + 1) * 16384 + (size_t)wv * 4096;
            const short* Wrf = ws + WS_RGR + (size_t)ll * 16384 + (size_t)wv * 4096;
            f32x4 acc[3][2][2];   // [matrix][graph][nt]
#pragma unroll
            for (int m = 0; m < 3; ++m)
#pragma unroll
                for (int g = 0; g < 2; ++g)
#pragma unroll
                    for (int j = 0; j < 2; ++j) acc[m][g][j] = (f32x4){0.f, 0.f, 0.f, 0.f};
#pragma unroll
            for (int ks = 0; ks < 4; ++ks) {
                h16x8 a0 = cvt8(HfS[0] + mrow * HLD + ks * 32 + q * 8);
                h16x8 a1 = cvt8(HfS[1] + mrow * HLD + ks * 32 + q * 8);
#pragma unroll
                for (int j = 0; j < 2; ++j) {
                    h16x8 b0 = ld8h(W0f + ((size_t)(j * 4 + ks) * 64 + l) * 8);
                    acc[0][0][j] = MFMA16(a0, b0, acc[0][0][j]);
                    acc[0][1][j] = MFMA16(a1, b0, acc[0][1][j]);
                    h16x8 b1 = ld8h(W1f + ((size_t)(j * 4 + ks) * 64 + l) * 8);
                    acc[1][0][j] = MFMA16(a0, b1, acc[1][0][j]);
                    acc[1][1][j] = MFMA16(a1, b1, acc[1][1][j]);
                    h16x8 br = ld8h(Wrf + ((size_t)(j * 4 + ks) * 64 + l) * 8);
                    acc[2][0][j] = MFMA16(a0, br, acc[2][0][j]);
                    acc[2][1][j] = MFMA16(a1, br, acc[2][1][j]);
                }
            }
#pragma unroll
            for (int m = 0; m < 3; ++m)
#pragma unroll
                for (int g = 0; g < 2; ++g)
                    storeC16<2, false>(acc[m][g], StS[g] + m * 128 + wv * 32, SLD, q, c16);
        }
        __syncthreads();
        // combine + LN + relu (VALU): wave wv owns tasks t = wv+4s, t=(g,i)
        {
            v2f rb2 = *(const v2f*)(rgcn_b + ll * D_ + 2 * l);
            short2 lnout[5];
#pragma unroll
            for (int s = 0; s < 5; ++s) {
                int t = wv + 4 * s;            // 0..19
                int g = (t >= 10) ? 1 : 0, i = t - g * 10;
                const short* St = StS[g];
                const float* C0 = C0S[g] + i * 10;
                const float* C1 = C1S[g] + i * 10;
                const float* As = AsS[g] + i * 10;
                v2f ag = splat2(rsAS[g][i]) * rb2;
#pragma unroll
                for (int j = 0; j < 10; ++j) {
                    short2 h0 = *(const short2*)(St + j * SLD + 2 * l);
                    short2 h1 = *(const short2*)(St + j * SLD + 128 + 2 * l);
                    short2 hr = *(const short2*)(St + j * SLD + 256 + 2 * l);
                    v2f v0; v0.x = hs2f(h0.x); v0.y = hs2f(h0.y);
                    v2f v1; v1.x = hs2f(h1.x); v1.y = hs2f(h1.y);
                    v2f vr; vr.x = hs2f(hr.x); vr.y = hs2f(hr.y);
                    ag = fma2(splat2(C0[j]), v0, ag);
                    ag = fma2(splat2(C1[j]), v1, ag);
                    ag = fma2(splat2(fabsf(As[j])), vr, ag);
                }
                float sm = ag.x + ag.y;
                float ss = fmaf(ag.x, ag.x, ag.y * ag.y);
#pragma unroll
                for (int off = 32; off > 0; off >>= 1) {
                    sm += __shfl_xor(sm, off);
                    ss += __shfl_xor(ss, off);
                }
                float mu   = sm * (1.f / 128.f);
                float var  = ss * (1.f / 128.f) - mu * mu;
                float rstd = rsqrtf(var + EPS_);
                v2f v = fma2((ag - splat2(mu)) * splat2(rstd), lg2, lb2);
                lnout[s].x = f2hs(fmaxf(v.x, 0.f));
                lnout[s].y = f2hs(fmaxf(v.y, 0.f));
            }
            __syncthreads();                   // all HW* reads done
#pragma unroll
            for (int s = 0; s < 5; ++s) {
                int t = wv + 4 * s;
                int g = (t >= 10) ? 1 : 0, i = t - g * 10;
                *(short2*)(StS[g] + i * SLD + 2 * l) = lnout[s];   // LNout -> cols 0:128
            }
        }
        __syncthreads();
        // MLP1: relu(LNout @ l1w + l1b): reads St[0:128], writes St[128:256]
        {
            f32x4 acc0[2], acc1[2];
            initC<2>(acc0, l1b + ll * D_ + wv * 32, c16);
            initC<2>(acc1, l1b + ll * D_ + wv * 32, c16);
            mm2_a16<4, 2>(ws + WS_L1 + (size_t)ll * 16384 + (size_t)wv * 4096,
                          StS[0], StS[1], SLD, mrow, q, l, acc0, acc1);
            storeC16<2, true>(acc0, StS[0] + 128 + wv * 32, SLD, q, c16);
            storeC16<2, true>(acc1, StS[1] + 128 + wv * 32, SLD, q, c16);
        }
        __syncthreads();
        // MLP2: hidden @ l2w + l2b: reads St[128:256], Hf += result
        {
            f32x4 acc0[2], acc1[2];
            initC<2>(acc0, l2b + ll * D_ + wv * 32, c16);
            initC<2>(acc1, l2b + ll * D_ + wv * 32, c16);
            mm2_a16<4, 2>(ws + WS_L2 + (size_t)ll * 16384 + (size_t)wv * 4096,
                          StS[0] + 128, StS[1] + 128, SLD, mrow, q, l, acc0, acc1);
#pragma unroll
            for (int j = 0; j < 2; ++j)
#pragma unroll
                for (int i = 0; i < 4; ++i) {
                    int r = q * 4 + i;
                    if (r < 10) {
                        HfS[0][r * HLD + wv * 32 + j * 16 + c16] += acc0[j][i];
                        HfS[1][r * HLD + wv * 32 + j * 16 + c16] += acc1[j][i];
                    }
                }
        }
        __syncthreads();
    }

    // ---- phi1: relu(H @ p1w + p1b) -> St[g][0:256]; wave wv: nt = 4wv..4wv+3 ----
    {
        f32x4 acc0[4], acc1[4];
        initC<4>(acc0, p1b + wv * 64, c16);
        initC<4>(acc1, p1b + wv * 64, c16);
        mm2_a32<4, 4>(ws + WS_P1 + (size_t)wv * 8192, HfS[0], HfS[1], HLD, mrow, q, l, acc0, acc1);
        storeC16<4, true>(acc0, StS[0] + wv * 64, SLD, q, c16);
        storeC16<4, true>(acc1, StS[1] + wv * 64, SLD, q, c16);
    }
    __syncthreads();
    // ---- phi2 + masked column sums -> RhoS[g]; wave wv: t = 4wv..4wv+3 ----
    {
        f32x4 acc0[4], acc1[4];
        initC<4>(acc0, p2b + wv * 64, c16);
        initC<4>(acc1, p2b + wv * 64, c16);
        mm2_a16<8, 4>(ws + WS_P2 + (size_t)wv * 16384, StS[0], StS[1], SLD, mrow, q, l, acc0, acc1);
#pragma unroll
        for (int g = 0; g < 2; ++g) {
            const f32x4* acc = g ? acc1 : acc0;
            float hm0 = hmfS[g][q * 4 + 0], hm1 = hmfS[g][q * 4 + 1];
            float hm2 = hmfS[g][q * 4 + 2], hm3 = hmfS[g][q * 4 + 3];
            float aw0 = awfS[g][q * 4 + 0], aw1 = awfS[g][q * 4 + 1];
            float aw2 = awfS[g][q * 4 + 2], aw3 = awfS[g][q * 4 + 3];
#pragma unroll
            for (int t = 0; t < 4; ++t) {
                float v0 = fmaxf(acc[t][0], 0.f), v1 = fmaxf(acc[t][1], 0.f);
                float v2 = fmaxf(acc[t][2], 0.f), v3 = fmaxf(acc[t][3], 0.f);
                float hp = hm0 * v0 + hm1 * v1 + hm2 * v2 + hm3 * v3;
                float ap = aw0 * v0 + aw1 * v1 + aw2 * v2 + aw3 * v3;
                hp += __shfl_xor(hp, 16); hp += __shfl_xor(hp, 32);
                ap += __shfl_xor(ap, 16); ap += __shfl_xor(ap, 32);
                if (l < 16) {
                    RhoS[g][(wv * 4 + t) * 16 + l]       = f2hs(hp);
                    RhoS[g][256 + (wv * 4 + t) * 16 + l] = f2hs(ap);
                }
            }
        }
    }
    __syncthreads();
    // ---- rho: relu([hs;aws] @ r1w + r1b) @ r2w; antisym difference ----
    {
        f32x4 acc0[2], acc1[2];
        initC<2>(acc0, r1b + wv * 32, c16);
        initC<2>(acc1, r1b + wv * 32, c16);
        const int rr = (c16 < 2) ? c16 : 0;
        mm2_a16<8, 2>(ws + WS_R1 + (size_t)wv * 8192, RhoS[0], RhoS[1], 256, rr, q, l, acc0, acc1);
#pragma unroll
        for (int g = 0; g < 2; ++g) {
            const f32x4* acc = g ? acc1 : acc0;
            float d = 0.f;
            if (q == 0) {
#pragma unroll
                for (int t = 0; t < 2; ++t) {
                    float vh = fmaxf(acc[t][0], 0.f);
                    float va = fmaxf(acc[t][1], 0.f);
                    d = fmaf(vh - va, r2w[(wv * 2 + t) * 16 + c16], d);
                }
            }
#pragma unroll
            for (int off = 32; off > 0; off >>= 1) d += __shfl_xor(d, off);
            if (l == 0) dS[g * 4 + wv] = d;
        }
    }
    __syncthreads();
    if (tid < 2)
        out[2 * b + tid] = 0.5f + 0.5f * tanhf(dS[tid * 4] + dS[tid * 4 + 1] +
                                               dS[tid * 4 + 2] + dS[tid * 4 + 3]);
}

extern "C" void kernel_launch(void* const* d_in, const int* in_sizes, int n_in,
                              void* d_out, int out_size, void* d_ws, size_t ws_size,
                              hipStream_t stream) {
    const float* A         = (const float*)d_in[0];
    const float* X         = (const float*)d_in[1];
    const int*   home_mask = (const int*)  d_in[2];
    const float* We1       = (const float*)d_in[3];
    const float* be1       = (const float*)d_in[4];
    const float* We2       = (const float*)d_in[5];
    const float* be2       = (const float*)d_in[6];
    const float* rgcn_w    = (const float*)d_in[7];
    const float* rgcn_root = (const float*)d_in[8];
    const float* rgcn_b    = (const float*)d_in[9];
    const float* l1w       = (const float*)d_in[10];
    const float* l1b       = (const float*)d_in[11];
    const float* l2w       = (const float*)d_in[12];
    const float* l2b       = (const float*)d_in[13];
    const float* ln_g      = (const float*)d_in[14];
    const float* ln_b      = (const float*)d_in[15];
    const float* p1w       = (const float*)d_in[16];
    const float* p1b       = (const float*)d_in[17];
    const float* p2w       = (const float*)d_in[18];
    const float* p2b       = (const float*)d_in[19];
    const float* r1w       = (const float*)d_in[20];
    const float* r1b       = (const float*)d_in[21];
    const float* r2w       = (const float*)d_in[22];

    short* ws = (short*)d_ws;

    prep_weights<<<776, 64, 0, stream>>>(We1, We2, rgcn_w, rgcn_root,
                                         l1w, l2w, p1w, p2w, r1w, ws);
    gcn_main<<<B_ / 2, 256, 0, stream>>>(A, X, home_mask, be1, be2, rgcn_b,
                                         l1b, l2b, ln_g, ln_b, p1b, p2b,
                                         r1b, r2w, ws, (float*)d_out);
}

// Round 5
// 263.581 us; speedup vs baseline: 1.0064x; 1.0064x over previous
//
#include <hip/hip_runtime.h>
#include <math.h>

#define B_    4096
#define N_    10
#define DIN_  32
#define D_    128
#define PHI_  256
#define RHO_  128
#define L_    3
#define EPS_  1e-5f

// ---- fp16 helpers (bits in short) ----
__device__ __forceinline__ short f2hs(float f) {            // f32 -> fp16 RNE
    union { _Float16 h; short s; } u;
    u.h = (_Float16)f;
    return u.s;
}
__device__ __forceinline__ float hs2f(short s) {
    union { _Float16 h; short s; } u;
    u.s = s;
    return (float)u.h;
}

typedef short    s16x8 __attribute__((ext_vector_type(8)));
typedef _Float16 h16x8 __attribute__((ext_vector_type(8)));
typedef float    f32x4 __attribute__((ext_vector_type(4)));
typedef float    v2f   __attribute__((ext_vector_type(2)));

__device__ __forceinline__ h16x8 ld8h(const short* p) {
    union { s16x8 s; h16x8 h; } u;
    u.s = *(const s16x8*)p;
    return u.h;
}
__device__ __forceinline__ h16x8 cvt8(const float* p) {     // 8 f32 -> 8 fp16
    f32x4 x0 = *(const f32x4*)p;
    f32x4 x1 = *(const f32x4*)(p + 4);
    h16x8 a;
    a[0]=(_Float16)x0[0]; a[1]=(_Float16)x0[1]; a[2]=(_Float16)x0[2]; a[3]=(_Float16)x0[3];
    a[4]=(_Float16)x1[0]; a[5]=(_Float16)x1[1]; a[6]=(_Float16)x1[2]; a[7]=(_Float16)x1[3];
    return a;
}

__device__ __forceinline__ v2f splat2(float s) { v2f r; r.x = s; r.y = s; return r; }
__device__ __forceinline__ v2f fma2(v2f a, v2f b, v2f c) { return __builtin_elementwise_fma(a, b, c); }

// ---- d_ws layout (fp16 elements). Fragment unit = 64 lanes x 8 el = 512 el.
// For matrix W[K][N]: frag (nt,ks) at ((nt*KS+ks)*64+lane)*8, lane holds
// W[ks*32+(lane>>4)*8+j][nt*16+(lane&15)], j=0..7  (B-operand layout, 16x16x32)
#define WS_WE1 0
#define WS_WE2 4096
#define WS_RGW 20480
#define WS_RGR 118784
#define WS_L1  167936
#define WS_L2  217088
#define WS_P1  266240
#define WS_P2  299008
#define WS_R1  364544

// ================= prep kernel: fp32 weights -> fp16 B-fragments ==========
__global__ __launch_bounds__(64)
void prep_weights(const float* __restrict__ We1, const float* __restrict__ We2,
                  const float* __restrict__ rgw, const float* __restrict__ rgr,
                  const float* __restrict__ l1w, const float* __restrict__ l2w,
                  const float* __restrict__ p1w, const float* __restrict__ p2w,
                  const float* __restrict__ r1w, short* __restrict__ ws)
{
    int bi = blockIdx.x, l = threadIdx.x;
    const float* src; int KS, Nw, dstOff, tt;
    if      (bi <   8) { src = We1; KS = 1; Nw = 128; dstOff = WS_WE1; tt = bi; }
    else if (bi <  40) { src = We2; KS = 4; Nw = 128; dstOff = WS_WE2; tt = bi - 8; }
    else if (bi < 232) { int m = (bi - 40) >> 5;  src = rgw + m * 16384; KS = 4; Nw = 128; dstOff = WS_RGW + m * 16384; tt = (bi - 40)  & 31; }
    else if (bi < 328) { int m = (bi - 232) >> 5; src = rgr + m * 16384; KS = 4; Nw = 128; dstOff = WS_RGR + m * 16384; tt = (bi - 232) & 31; }
    else if (bi < 424) { int m = (bi - 328) >> 5; src = l1w + m * 16384; KS = 4; Nw = 128; dstOff = WS_L1  + m * 16384; tt = (bi - 328) & 31; }
    else if (bi < 520) { int m = (bi - 424) >> 5; src = l2w + m * 16384; KS = 4; Nw = 128; dstOff = WS_L2  + m * 16384; tt = (bi - 424) & 31; }
    else if (bi < 584) { src = p1w; KS = 4; Nw = 256; dstOff = WS_P1; tt = bi - 520; }
    else if (bi < 712) { src = p2w; KS = 8; Nw = 256; dstOff = WS_P2; tt = bi - 584; }
    else               { src = r1w; KS = 8; Nw = 128; dstOff = WS_R1; tt = bi - 712; }
    int nt = tt / KS, ks = tt - nt * KS;
    int kbase = ks * 32 + (l >> 4) * 8;
    int col   = nt * 16 + (l & 15);
    union { short s[8]; int4 v; } u;
#pragma unroll
    for (int j = 0; j < 8; ++j)
        u.s[j] = f2hs(src[(size_t)(kbase + j) * Nw + col]);
    *(int4*)(ws + dstOff + ((size_t)tt * 64 + l) * 8) = u.v;
}

// ================= main kernel: 1 block (4 waves) = 2 graphs ===============
// Each weight B-fragment is loaded ONCE per wave and used for 2 MFMAs (one
// per graph) -> L2 weight traffic halves vs 1 graph/block.
// A-operand layout: lane holds A[m=lane&15][k=(lane>>4)*8+j]; rows >=10 clamped
// C/D layout: col = lane&15, row = (lane>>4)*4 + reg

template<int NTP>
__device__ __forceinline__ void initC(f32x4* acc, const float* __restrict__ bias, int c16) {
#pragma unroll
    for (int j = 0; j < NTP; ++j) {
        float bv = bias[j * 16 + c16];
        acc[j] = (f32x4){bv, bv, bv, bv};
    }
}

#define MFMA16(a, b, c) __builtin_amdgcn_mfma_f32_16x16x32_f16(a, b, c, 0, 0, 0)

// dual-graph matmul, fp16 A from LDS
template<int KS, int NTP>
__device__ __forceinline__ void mm2_a16(const short* __restrict__ Wf,
                                        const short* __restrict__ A0, const short* __restrict__ A1,
                                        int ldA, int mrow, int q, int l,
                                        f32x4* acc0, f32x4* acc1) {
#pragma unroll
    for (int ks = 0; ks < KS; ++ks) {
        h16x8 a0 = ld8h(A0 + mrow * ldA + ks * 32 + q * 8);
        h16x8 a1 = ld8h(A1 + mrow * ldA + ks * 32 + q * 8);
#pragma unroll
        for (int j = 0; j < NTP; ++j) {
            h16x8 bv = ld8h(Wf + ((size_t)(j * KS + ks) * 64 + l) * 8);
            acc0[j] = MFMA16(a0, bv, acc0[j]);
            acc1[j] = MFMA16(a1, bv, acc1[j]);
        }
    }
}

// dual-graph matmul, fp32 A from LDS (converted per k-slice)
template<int KS, int NTP>
__device__ __forceinline__ void mm2_a32(const short* __restrict__ Wf,
                                        const float* __restrict__ A0, const float* __restrict__ A1,
                                        int ldA, int mrow, int q, int l,
                                        f32x4* acc0, f32x4* acc1) {
#pragma unroll
    for (int ks = 0; ks < KS; ++ks) {
        h16x8 a0 = cvt8(A0 + mrow * ldA + ks * 32 + q * 8);
        h16x8 a1 = cvt8(A1 + mrow * ldA + ks * 32 + q * 8);
#pragma unroll
        for (int j = 0; j < NTP; ++j) {
            h16x8 bv = ld8h(Wf + ((size_t)(j * KS + ks) * 64 + l) * 8);
            acc0[j] = MFMA16(a0, bv, acc0[j]);
            acc1[j] = MFMA16(a1, bv, acc1[j]);
        }
    }
}

// store C tiles as fp16 into LDS (row-major, ldD elements), rows >= 10 dropped.
template<int NTP, bool RELU>
__device__ __forceinline__ void storeC16(const f32x4* acc, short* __restrict__ dst,
                                         int ldD, int q, int c16) {
#pragma unroll
    for (int j = 0; j < NTP; ++j) {
#pragma unroll
        for (int i = 0; i < 4; ++i) {
            int r = q * 4 + i;
            if (r < 10) {
                float v = acc[j][i];
                if (RELU) v = fmaxf(v, 0.f);
                dst[r * ldD + j * 16 + c16] = f2hs(v);
            }
        }
    }
}

#define HLD 132   // Hf row stride (f32); %32 words = 4 -> worst 2-way (free)
#define SLD 392   // staging row stride (fp16); 784 B rows, 16B-aligned, 2-way max

// waves_per_eu(4,4): round-4's launch_bounds(256,4) left the allocator a
// [4,8] occupancy range; it targeted 8 (64-VGPR budget) and SPILLED the
// fused RGCN phase (~160 MB/dispatch scratch traffic: WRITE 97 MB).
// Pinning min=max=4 gives a 128-VGPR budget -> no spill. Runtime occupancy
// is LDS/VGPR-capped at 4 blocks/CU either way.
__global__ __attribute__((amdgpu_waves_per_eu(4, 4))) __launch_bounds__(256)
void gcn_main(const float* __restrict__ A, const float* __restrict__ X,
              const int* __restrict__ home_mask,
              const float* __restrict__ be1, const float* __restrict__ be2,
              const float* __restrict__ rgcn_b,
              const float* __restrict__ l1b, const float* __restrict__ l2b,
              const float* __restrict__ ln_g, const float* __restrict__ ln_b,
              const float* __restrict__ p1b, const float* __restrict__ p2b,
              const float* __restrict__ r1b, const float* __restrict__ r2w,
              const short* __restrict__ ws, float* __restrict__ out)
{
    const int b   = blockIdx.x;        // graph pair: graphs 2b, 2b+1
    const int tid = threadIdx.x;       // 0..255
    const int wv  = tid >> 6;          // wave 0..3 (owns nt = wv*NTP ..)
    const int l   = tid & 63;          // lane
    const int q   = l >> 4;
    const int c16 = l & 15;
    const int mrow = (c16 < 10) ? c16 : 9;

    // per-graph state (31.2 KB total)
    __shared__ __align__(16) float HfS[2][N_ * HLD];   // residual H, fp32
    __shared__ __align__(16) short StS[2][N_ * SLD];   // staging: HW0|HW1|HWr / LN|hidden / phi
    __shared__ __align__(16) short RhoS[2][512];       // [hs ; aws] fp16
    __shared__ float AsS[2][100];                      // signed A
    __shared__ float C0S[2][100], C1S[2][100];         // |A|·D0·M0^T etc (layer-invariant)
    __shared__ float invc0S[2][N_], invc1S[2][N_], rsAS[2][N_];
    __shared__ float hmfS[2][16], awfS[2][16];
    __shared__ float dS[8];

    // ---- phase 0: stage A (signed) + masks + embed1 ----
    if (tid < 200) {
        int g = tid / 100, e = tid - g * 100;
        AsS[g][e] = A[(size_t)(2 * b + g) * 100 + e];
    }
    if (tid < 32) {
        int g = tid >> 4, idx = tid & 15;
        float hm = 0.f, aw = 0.f;
        if (idx < 10) { hm = (float)home_mask[(2 * b + g) * N_ + idx]; aw = 1.f - hm; }
        hmfS[g][idx] = hm; awfS[g][idx] = aw;
    }
    {   // embed1: H1 = relu(X@We1 + be1) -> St[g][0:128]; shared B-frags
        f32x4 acc0[2], acc1[2];
        initC<2>(acc0, be1 + wv * 32, c16);
        initC<2>(acc1, be1 + wv * 32, c16);
        h16x8 a0 = cvt8(X + (size_t)(2 * b + 0) * (N_ * DIN_) + mrow * DIN_ + q * 8);
        h16x8 a1 = cvt8(X + (size_t)(2 * b + 1) * (N_ * DIN_) + mrow * DIN_ + q * 8);
#pragma unroll
        for (int j = 0; j < 2; ++j) {
            h16x8 bv = ld8h(ws + WS_WE1 + ((size_t)(wv * 2 + j) * 64 + l) * 8);
            acc0[j] = MFMA16(a0, bv, acc0[j]);
            acc1[j] = MFMA16(a1, bv, acc1[j]);
        }
        storeC16<2, true>(acc0, StS[0] + wv * 32, SLD, q, c16);
        storeC16<2, true>(acc1, StS[1] + wv * 32, SLD, q, c16);
    }
    __syncthreads();

    // ---- phase 1: invc + rsA (VALU) + embed2 (MFMA) ----
    if (tid < 20) {
        int g = tid / 10, j = tid - g * 10;
        float c1 = 0.f;
#pragma unroll
        for (int i = 0; i < 10; ++i) c1 += (AsS[g][i * 10 + j] > 0.f) ? 1.f : 0.f;
        invc1S[g][j] = 1.f / fmaxf(c1, 1.f);
        invc0S[g][j] = 1.f / fmaxf(10.f - c1, 1.f);
        float r = 0.f;
#pragma unroll
        for (int k = 0; k < 10; ++k) r += fabsf(AsS[g][j * 10 + k]);
        rsAS[g][j] = r;
    }
    {   // embed2: H = H1@We2 + be2 -> Hf (fp32)
        f32x4 acc0[2], acc1[2];
        initC<2>(acc0, be2 + wv * 32, c16);
        initC<2>(acc1, be2 + wv * 32, c16);
        mm2_a16<4, 2>(ws + WS_WE2 + (size_t)wv * 4096, StS[0], StS[1], SLD, mrow, q, l, acc0, acc1);
#pragma unroll
        for (int j = 0; j < 2; ++j)
#pragma unroll
            for (int i = 0; i < 4; ++i) {
                int r = q * 4 + i;
                if (r < 10) {
                    HfS[0][r * HLD + wv * 32 + j * 16 + c16] = acc0[j][i];
                    HfS[1][r * HLD + wv * 32 + j * 16 + c16] = acc1[j][i];
                }
            }
    }
    __syncthreads();

    // ---- phase 2: coefficient matrices (layer-invariant):
    //   agg = |A|·H2, H2 = D0·M0^T·HW0 + D1·M1^T·HW1 + HWr + 1·b^T
    //   => agg[i] = sum_k C0[i,k]·HW0[k] + C1[i,k]·HW1[k] + |A[i,k]|·HWr[k] + rsA[i]·b
    //   C0[i,k] = sum_j |A[i,j]|·invc0[j]·M0[k,j]
    if (tid < 200) {
        int g = tid / 100, e = tid - g * 100;
        int i = e / 10, k = e - i * 10;
        const float* As = AsS[g];
        float c0 = 0.f, c1 = 0.f;
#pragma unroll
        for (int j = 0; j < 10; ++j) {
            float aij = fabsf(As[i * 10 + j]);
            if (As[k * 10 + j] > 0.f) c1 += aij * invc1S[g][j];
            else                      c0 += aij * invc0S[g][j];
        }
        C0S[g][e] = c0; C1S[g][e] = c1;
    }
    __syncthreads();

    const v2f lg2 = *(const v2f*)(ln_g + 2 * l);
    const v2f lb2 = *(const v2f*)(ln_b + 2 * l);

    // ---- layers ----
    for (int ll = 0; ll < L_; ++ll) {
        // fused RGCN matmuls: HW0|HW1|HWr -> St[g][0:384] (shared A-cvt)
        {
            const short* W0f = ws + WS_RGW + (size_t)(ll * 2 + 0) * 16384 + (size_t)wv * 4096;
            const short* W1f = ws + WS_RGW + (size_t)(ll * 2 + 1) * 16384 + (size_t)wv * 4096;
            const short* Wrf = ws + WS_RGR + (size_t)ll * 16384 + (size_t)wv * 4096;
            f32x4 acc[3][2][2];   // [matrix][graph][nt]
#pragma unroll
            for (int m = 0; m < 3; ++m)
#pragma unroll
                for (int g = 0; g < 2; ++g)
#pragma unroll
                    for (int j = 0; j < 2; ++j) acc[m][g][j] = (f32x4){0.f, 0.f, 0.f, 0.f};
#pragma unroll
            for (int ks = 0; ks < 4; ++ks) {
                h16x8 a0 = cvt8(HfS[0] + mrow * HLD + ks * 32 + q * 8);
                h16x8 a1 = cvt8(HfS[1] + mrow * HLD + ks * 32 + q * 8);
#pragma unroll
                for (int j = 0; j < 2; ++j) {
                    h16x8 b0 = ld8h(W0f + ((size_t)(j * 4 + ks) * 64 + l) * 8);
                    acc[0][0][j] = MFMA16(a0, b0, acc[0][0][j]);
                    acc[0][1][j] = MFMA16(a1, b0, acc[0][1][j]);
                    h16x8 b1 = ld8h(W1f + ((size_t)(j * 4 + ks) * 64 + l) * 8);
                    acc[1][0][j] = MFMA16(a0, b1, acc[1][0][j]);
                    acc[1][1][j] = MFMA16(a1, b1, acc[1][1][j]);
                    h16x8 br = ld8h(Wrf + ((size_t)(j * 4 + ks) * 64 + l) * 8);
                    acc[2][0][j] = MFMA16(a0, br, acc[2][0][j]);
                    acc[2][1][j] = MFMA16(a1, br, acc[2][1][j]);
                }
            }
#pragma unroll
            for (int m = 0; m < 3; ++m)
#pragma unroll
                for (int g = 0; g < 2; ++g)
                    storeC16<2, false>(acc[m][g], StS[g] + m * 128 + wv * 32, SLD, q, c16);
        }
        __syncthreads();
        // combine + LN + relu (VALU): wave wv owns tasks t = wv+4s, t=(g,i)
        {
            v2f rb2 = *(const v2f*)(rgcn_b + ll * D_ + 2 * l);
            short2 lnout[5];
#pragma unroll
            for (int s = 0; s < 5; ++s) {
                int t = wv + 4 * s;            // 0..19
                int g = (t >= 10) ? 1 : 0, i = t - g * 10;
                const short* St = StS[g];
                const float* C0 = C0S[g] + i * 10;
                const float* C1 = C1S[g] + i * 10;
                const float* As = AsS[g] + i * 10;
                v2f ag = splat2(rsAS[g][i]) * rb2;
#pragma unroll
                for (int j = 0; j < 10; ++j) {
                    short2 h0 = *(const short2*)(St + j * SLD + 2 * l);
                    short2 h1 = *(const short2*)(St + j * SLD + 128 + 2 * l);
                    short2 hr = *(const short2*)(St + j * SLD + 256 + 2 * l);
                    v2f v0; v0.x = hs2f(h0.x); v0.y = hs2f(h0.y);
                    v2f v1; v1.x = hs2f(h1.x); v1.y = hs2f(h1.y);
                    v2f vr; vr.x = hs2f(hr.x); vr.y = hs2f(hr.y);
                    ag = fma2(splat2(C0[j]), v0, ag);
                    ag = fma2(splat2(C1[j]), v1, ag);
                    ag = fma2(splat2(fabsf(As[j])), vr, ag);
                }
                float sm = ag.x + ag.y;
                float ss = fmaf(ag.x, ag.x, ag.y * ag.y);
#pragma unroll
                for (int off = 32; off > 0; off >>= 1) {
                    sm += __shfl_xor(sm, off);
                    ss += __shfl_xor(ss, off);
                }
                float mu   = sm * (1.f / 128.f);
                float var  = ss * (1.f / 128.f) - mu * mu;
                float rstd = rsqrtf(var + EPS_);
                v2f v = fma2((ag - splat2(mu)) * splat2(rstd), lg2, lb2);
                lnout[s].x = f2hs(fmaxf(v.x, 0.f));
                lnout[s].y = f2hs(fmaxf(v.y, 0.f));
            }
            __syncthreads();                   // all HW* reads done
#pragma unroll
            for (int s = 0; s < 5; ++s) {
                int t = wv + 4 * s;
                int g = (t >= 10) ? 1 : 0, i = t - g * 10;
                *(short2*)(StS[g] + i * SLD + 2 * l) = lnout[s];   // LNout -> cols 0:128
            }
        }
        __syncthreads();
        // MLP1: relu(LNout @ l1w + l1b): reads St[0:128], writes St[128:256]
        {
            f32x4 acc0[2], acc1[2];
            initC<2>(acc0, l1b + ll * D_ + wv * 32, c16);
            initC<2>(acc1, l1b + ll * D_ + wv * 32, c16);
            mm2_a16<4, 2>(ws + WS_L1 + (size_t)ll * 16384 + (size_t)wv * 4096,
                          StS[0], StS[1], SLD, mrow, q, l, acc0, acc1);
            storeC16<2, true>(acc0, StS[0] + 128 + wv * 32, SLD, q, c16);
            storeC16<2, true>(acc1, StS[1] + 128 + wv * 32, SLD, q, c16);
        }
        __syncthreads();
        // MLP2: hidden @ l2w + l2b: reads St[128:256], Hf += result
        {
            f32x4 acc0[2], acc1[2];
            initC<2>(acc0, l2b + ll * D_ + wv * 32, c16);
            initC<2>(acc1, l2b + ll * D_ + wv * 32, c16);
            mm2_a16<4, 2>(ws + WS_L2 + (size_t)ll * 16384 + (size_t)wv * 4096,
                          StS[0] + 128, StS[1] + 128, SLD, mrow, q, l, acc0, acc1);
#pragma unroll
            for (int j = 0; j < 2; ++j)
#pragma unroll
                for (int i = 0; i < 4; ++i) {
                    int r = q * 4 + i;
                    if (r < 10) {
                        HfS[0][r * HLD + wv * 32 + j * 16 + c16] += acc0[j][i];
                        HfS[1][r * HLD + wv * 32 + j * 16 + c16] += acc1[j][i];
                    }
                }
        }
        __syncthreads();
    }

    // ---- phi1: relu(H @ p1w + p1b) -> St[g][0:256]; wave wv: nt = 4wv..4wv+3 ----
    {
        f32x4 acc0[4], acc1[4];
        initC<4>(acc0, p1b + wv * 64, c16);
        initC<4>(acc1, p1b + wv * 64, c16);
        mm2_a32<4, 4>(ws + WS_P1 + (size_t)wv * 8192, HfS[0], HfS[1], HLD, mrow, q, l, acc0, acc1);
        storeC16<4, true>(acc0, StS[0] + wv * 64, SLD, q, c16);
        storeC16<4, true>(acc1, StS[1] + wv * 64, SLD, q, c16);
    }
    __syncthreads();
    // ---- phi2 + masked column sums -> RhoS[g]; wave wv: t = 4wv..4wv+3 ----
    {
        f32x4 acc0[4], acc1[4];
        initC<4>(acc0, p2b + wv * 64, c16);
        initC<4>(acc1, p2b + wv * 64, c16);
        mm2_a16<8, 4>(ws + WS_P2 + (size_t)wv * 16384, StS[0], StS[1], SLD, mrow, q, l, acc0, acc1);
#pragma unroll
        for (int g = 0; g < 2; ++g) {
            const f32x4* acc = g ? acc1 : acc0;
            float hm0 = hmfS[g][q * 4 + 0], hm1 = hmfS[g][q * 4 + 1];
            float hm2 = hmfS[g][q * 4 + 2], hm3 = hmfS[g][q * 4 + 3];
            float aw0 = awfS[g][q * 4 + 0], aw1 = awfS[g][q * 4 + 1];
            float aw2 = awfS[g][q * 4 + 2], aw3 = awfS[g][q * 4 + 3];
#pragma unroll
            for (int t = 0; t < 4; ++t) {
                float v0 = fmaxf(acc[t][0], 0.f), v1 = fmaxf(acc[t][1], 0.f);
                float v2 = fmaxf(acc[t][2], 0.f), v3 = fmaxf(acc[t][3], 0.f);
                float hp = hm0 * v0 + hm1 * v1 + hm2 * v2 + hm3 * v3;
                float ap = aw0 * v0 + aw1 * v1 + aw2 * v2 + aw3 * v3;
                hp += __shfl_xor(hp, 16); hp += __shfl_xor(hp, 32);
                ap += __shfl_xor(ap, 16); ap += __shfl_xor(ap, 32);
                if (l < 16) {
                    RhoS[g][(wv * 4 + t) * 16 + l]       = f2hs(hp);
                    RhoS[g][256 + (wv * 4 + t) * 16 + l] = f2hs(ap);
                }
            }
        }
    }
    __syncthreads();
    // ---- rho: relu([hs;aws] @ r1w + r1b) @ r2w; antisym difference ----
    {
        f32x4 acc0[2], acc1[2];
        initC<2>(acc0, r1b + wv * 32, c16);
        initC<2>(acc1, r1b + wv * 32, c16);
        const int rr = (c16 < 2) ? c16 : 0;
        mm2_a16<8, 2>(ws + WS_R1 + (size_t)wv * 8192, RhoS[0], RhoS[1], 256, rr, q, l, acc0, acc1);
#pragma unroll
        for (int g = 0; g < 2; ++g) {
            const f32x4* acc = g ? acc1 : acc0;
            float d = 0.f;
            if (q == 0) {
#pragma unroll
                for (int t = 0; t < 2; ++t) {
                    float vh = fmaxf(acc[t][0], 0.f);
                    float va = fmaxf(acc[t][1], 0.f);
                    d = fmaf(vh - va, r2w[(wv * 2 + t) * 16 + c16], d);
                }
            }
#pragma unroll
            for (int off = 32; off > 0; off >>= 1) d += __shfl_xor(d, off);
            if (l == 0) dS[g * 4 + wv] = d;
        }
    }
    __syncthreads();
    if (tid < 2)
        out[2 * b + tid] = 0.5f + 0.5f * tanhf(dS[tid * 4] + dS[tid * 4 + 1] +
                                               dS[tid * 4 + 2] + dS[tid * 4 + 3]);
}

extern "C" void kernel_launch(void* const* d_in, const int* in_sizes, int n_in,
                              void* d_out, int out_size, void* d_ws, size_t ws_size,
                              hipStream_t stream) {
    const float* A         = (const float*)d_in[0];
    const float* X         = (const float*)d_in[1];
    const int*   home_mask = (const int*)  d_in[2];
    const float* We1       = (const float*)d_in[3];
    const float* be1       = (const float*)d_in[4];
    const float* We2       = (const float*)d_in[5];
    const float* be2       = (const float*)d_in[6];
    const float* rgcn_w    = (const float*)d_in[7];
    const float* rgcn_root = (const float*)d_in[8];
    const float* rgcn_b    = (const float*)d_in[9];
    const float* l1w       = (const float*)d_in[10];
    const float* l1b       = (const float*)d_in[11];
    const float* l2w       = (const float*)d_in[12];
    const float* l2b       = (const float*)d_in[13];
    const float* ln_g      = (const float*)d_in[14];
    const float* ln_b      = (const float*)d_in[15];
    const float* p1w       = (const float*)d_in[16];
    const float* p1b       = (const float*)d_in[17];
    const float* p2w       = (const float*)d_in[18];
    const float* p2b       = (const float*)d_in[19];
    const float* r1w       = (const float*)d_in[20];
    const float* r1b       = (const float*)d_in[21];
    const float* r2w       = (const float*)d_in[22];

    short* ws = (short*)d_ws;

    prep_weights<<<776, 64, 0, stream>>>(We1, We2, rgcn_w, rgcn_root,
                                         l1w, l2w, p1w, p2w, r1w, ws);
    gcn_main<<<B_ / 2, 256, 0, stream>>>(A, X, home_mask, be1, be2, rgcn_b,
                                         l1b, l2b, ln_g, ln_b, p1b, p2b,
                                         r1b, r2w, ws, (float*)d_out);
}

// Round 6
// 247.050 us; speedup vs baseline: 1.0738x; 1.0669x over previous
//
#include <hip/hip_runtime.h>
#include <math.h>

#define B_    4096
#define N_    10
#define DIN_  32
#define D_    128
#define PHI_  256
#define RHO_  128
#define L_    3
#define EPS_  1e-5f

// ---- fp16 helpers (bits in short) ----
__device__ __forceinline__ short f2hs(float f) {            // f32 -> fp16 RNE
    union { _Float16 h; short s; } u;
    u.h = (_Float16)f;
    return u.s;
}
__device__ __forceinline__ float hs2f(short s) {
    union { _Float16 h; short s; } u;
    u.s = s;
    return (float)u.h;
}

typedef short    s16x8 __attribute__((ext_vector_type(8)));
typedef _Float16 h16x8 __attribute__((ext_vector_type(8)));
typedef float    f32x4 __attribute__((ext_vector_type(4)));
typedef float    v2f   __attribute__((ext_vector_type(2)));

__device__ __forceinline__ h16x8 ld8h(const short* p) {
    union { s16x8 s; h16x8 h; } u;
    u.s = *(const s16x8*)p;
    return u.h;
}
__device__ __forceinline__ h16x8 cvt8(const float* p) {     // 8 f32 -> 8 fp16
    f32x4 x0 = *(const f32x4*)p;
    f32x4 x1 = *(const f32x4*)(p + 4);
    h16x8 a;
    a[0]=(_Float16)x0[0]; a[1]=(_Float16)x0[1]; a[2]=(_Float16)x0[2]; a[3]=(_Float16)x0[3];
    a[4]=(_Float16)x1[0]; a[5]=(_Float16)x1[1]; a[6]=(_Float16)x1[2]; a[7]=(_Float16)x1[3];
    return a;
}

__device__ __forceinline__ v2f splat2(float s) { v2f r; r.x = s; r.y = s; return r; }
__device__ __forceinline__ v2f fma2(v2f a, v2f b, v2f c) { return __builtin_elementwise_fma(a, b, c); }

// ---- d_ws layout (fp16 elements). Fragment unit = 64 lanes x 8 el = 512 el.
// For matrix W[K][N]: frag (nt,ks) at ((nt*KS+ks)*64+lane)*8, lane holds
// W[ks*32+(lane>>4)*8+j][nt*16+(lane&15)], j=0..7  (B-operand layout, 16x16x32)
#define WS_WE1 0
#define WS_WE2 4096
#define WS_RGW 20480
#define WS_RGR 118784
#define WS_L1  167936
#define WS_L2  217088
#define WS_P1  266240
#define WS_P2  299008
#define WS_R1  364544

// ================= prep kernel: fp32 weights -> fp16 B-fragments ==========
__global__ __launch_bounds__(64)
void prep_weights(const float* __restrict__ We1, const float* __restrict__ We2,
                  const float* __restrict__ rgw, const float* __restrict__ rgr,
                  const float* __restrict__ l1w, const float* __restrict__ l2w,
                  const float* __restrict__ p1w, const float* __restrict__ p2w,
                  const float* __restrict__ r1w, short* __restrict__ ws)
{
    int bi = blockIdx.x, l = threadIdx.x;
    const float* src; int KS, Nw, dstOff, tt;
    if      (bi <   8) { src = We1; KS = 1; Nw = 128; dstOff = WS_WE1; tt = bi; }
    else if (bi <  40) { src = We2; KS = 4; Nw = 128; dstOff = WS_WE2; tt = bi - 8; }
    else if (bi < 232) { int m = (bi - 40) >> 5;  src = rgw + m * 16384; KS = 4; Nw = 128; dstOff = WS_RGW + m * 16384; tt = (bi - 40)  & 31; }
    else if (bi < 328) { int m = (bi - 232) >> 5; src = rgr + m * 16384; KS = 4; Nw = 128; dstOff = WS_RGR + m * 16384; tt = (bi - 232) & 31; }
    else if (bi < 424) { int m = (bi - 328) >> 5; src = l1w + m * 16384; KS = 4; Nw = 128; dstOff = WS_L1  + m * 16384; tt = (bi - 328) & 31; }
    else if (bi < 520) { int m = (bi - 424) >> 5; src = l2w + m * 16384; KS = 4; Nw = 128; dstOff = WS_L2  + m * 16384; tt = (bi - 424) & 31; }
    else if (bi < 584) { src = p1w; KS = 4; Nw = 256; dstOff = WS_P1; tt = bi - 520; }
    else if (bi < 712) { src = p2w; KS = 8; Nw = 256; dstOff = WS_P2; tt = bi - 584; }
    else               { src = r1w; KS = 8; Nw = 128; dstOff = WS_R1; tt = bi - 712; }
    int nt = tt / KS, ks = tt - nt * KS;
    int kbase = ks * 32 + (l >> 4) * 8;
    int col   = nt * 16 + (l & 15);
    union { short s[8]; int4 v; } u;
#pragma unroll
    for (int j = 0; j < 8; ++j)
        u.s[j] = f2hs(src[(size_t)(kbase + j) * Nw + col]);
    *(int4*)(ws + dstOff + ((size_t)tt * 64 + l) * 8) = u.v;
}

// ================= main kernel: 1 block (4 waves) = 2 graphs ===============
// Every phase keeps peak live VGPRs <= ~56 (the allocator's revealed budget
// is 64): NTP<=2 per pass, NO runtime pointer selects into register arrays
// (rule #20: `g ? acc1 : acc0` forces both arrays to scratch -> the 160 MB
// scratch traffic seen in rounds 4/5).
// A-operand layout: lane holds A[m=lane&15][k=(lane>>4)*8+j]; rows >=10 clamped
// C/D layout: col = lane&15, row = (lane>>4)*4 + reg

template<int NTP>
__device__ __forceinline__ void initC(f32x4* acc, const float* __restrict__ bias, int c16) {
#pragma unroll
    for (int j = 0; j < NTP; ++j) {
        float bv = bias[j * 16 + c16];
        acc[j] = (f32x4){bv, bv, bv, bv};
    }
}

#define MFMA16(a, b, c) __builtin_amdgcn_mfma_f32_16x16x32_f16(a, b, c, 0, 0, 0)

// dual-graph matmul, fp16 A from LDS
template<int KS, int NTP>
__device__ __forceinline__ void mm2_a16(const short* __restrict__ Wf,
                                        const short* __restrict__ A0, const short* __restrict__ A1,
                                        int ldA, int mrow, int q, int l,
                                        f32x4* acc0, f32x4* acc1) {
#pragma unroll
    for (int ks = 0; ks < KS; ++ks) {
        h16x8 a0 = ld8h(A0 + mrow * ldA + ks * 32 + q * 8);
        h16x8 a1 = ld8h(A1 + mrow * ldA + ks * 32 + q * 8);
#pragma unroll
        for (int j = 0; j < NTP; ++j) {
            h16x8 bv = ld8h(Wf + ((size_t)(j * KS + ks) * 64 + l) * 8);
            acc0[j] = MFMA16(a0, bv, acc0[j]);
            acc1[j] = MFMA16(a1, bv, acc1[j]);
        }
    }
}

// dual-graph matmul, fp32 A from LDS (converted per k-slice)
template<int KS, int NTP>
__device__ __forceinline__ void mm2_a32(const short* __restrict__ Wf,
                                        const float* __restrict__ A0, const float* __restrict__ A1,
                                        int ldA, int mrow, int q, int l,
                                        f32x4* acc0, f32x4* acc1) {
#pragma unroll
    for (int ks = 0; ks < KS; ++ks) {
        h16x8 a0 = cvt8(A0 + mrow * ldA + ks * 32 + q * 8);
        h16x8 a1 = cvt8(A1 + mrow * ldA + ks * 32 + q * 8);
#pragma unroll
        for (int j = 0; j < NTP; ++j) {
            h16x8 bv = ld8h(Wf + ((size_t)(j * KS + ks) * 64 + l) * 8);
            acc0[j] = MFMA16(a0, bv, acc0[j]);
            acc1[j] = MFMA16(a1, bv, acc1[j]);
        }
    }
}

// store C tiles as fp16 into LDS (row-major, ldD elements), rows >= 10 dropped.
template<int NTP, bool RELU>
__device__ __forceinline__ void storeC16(const f32x4* acc, short* __restrict__ dst,
                                         int ldD, int q, int c16) {
#pragma unroll
    for (int j = 0; j < NTP; ++j) {
#pragma unroll
        for (int i = 0; i < 4; ++i) {
            int r = q * 4 + i;
            if (r < 10) {
                float v = acc[j][i];
                if (RELU) v = fmaxf(v, 0.f);
                dst[r * ldD + j * 16 + c16] = f2hs(v);
            }
        }
    }
}

#define HLD 132   // Hf row stride (f32)
#define SLD 392   // staging row stride (fp16)

__global__ __launch_bounds__(256, 4)
void gcn_main(const float* __restrict__ A, const float* __restrict__ X,
              const int* __restrict__ home_mask,
              const float* __restrict__ be1, const float* __restrict__ be2,
              const float* __restrict__ rgcn_b,
              const float* __restrict__ l1b, const float* __restrict__ l2b,
              const float* __restrict__ ln_g, const float* __restrict__ ln_b,
              const float* __restrict__ p1b, const float* __restrict__ p2b,
              const float* __restrict__ r1b, const float* __restrict__ r2w,
              const short* __restrict__ ws, float* __restrict__ out)
{
    const int b   = blockIdx.x;        // graph pair: graphs 2b, 2b+1
    const int tid = threadIdx.x;       // 0..255
    const int wv  = tid >> 6;          // wave 0..3
    const int l   = tid & 63;          // lane
    const int q   = l >> 4;
    const int c16 = l & 15;
    const int mrow = (c16 < 10) ? c16 : 9;

    // per-graph state (31.2 KB total -> LDS caps at 5 blocks/CU)
    __shared__ __align__(16) float HfS[2][N_ * HLD];   // residual H, fp32
    __shared__ __align__(16) short StS[2][N_ * SLD];   // staging: HW0|HW1|HWr / LN|hidden / phi
    __shared__ __align__(16) short RhoS[2][512];       // [hs ; aws] fp16
    __shared__ float AsS[2][100];                      // signed A
    __shared__ float C0S[2][100], C1S[2][100];         // |A|·D0·M0^T etc (layer-invariant)
    __shared__ float invc0S[2][N_], invc1S[2][N_], rsAS[2][N_];
    __shared__ float hmfS[2][16], awfS[2][16];
    __shared__ float dS[8];

    // ---- phase 0: stage A (signed) + masks + embed1 ----
    if (tid < 200) {
        int g = tid / 100, e = tid - g * 100;
        AsS[g][e] = A[(size_t)(2 * b + g) * 100 + e];
    }
    if (tid < 32) {
        int g = tid >> 4, idx = tid & 15;
        float hm = 0.f, aw = 0.f;
        if (idx < 10) { hm = (float)home_mask[(2 * b + g) * N_ + idx]; aw = 1.f - hm; }
        hmfS[g][idx] = hm; awfS[g][idx] = aw;
    }
    {   // embed1: H1 = relu(X@We1 + be1) -> St[g][0:128]; shared B-frags
        f32x4 acc0[2], acc1[2];
        initC<2>(acc0, be1 + wv * 32, c16);
        initC<2>(acc1, be1 + wv * 32, c16);
        h16x8 a0 = cvt8(X + (size_t)(2 * b + 0) * (N_ * DIN_) + mrow * DIN_ + q * 8);
        h16x8 a1 = cvt8(X + (size_t)(2 * b + 1) * (N_ * DIN_) + mrow * DIN_ + q * 8);
#pragma unroll
        for (int j = 0; j < 2; ++j) {
            h16x8 bv = ld8h(ws + WS_WE1 + ((size_t)(wv * 2 + j) * 64 + l) * 8);
            acc0[j] = MFMA16(a0, bv, acc0[j]);
            acc1[j] = MFMA16(a1, bv, acc1[j]);
        }
        storeC16<2, true>(acc0, StS[0] + wv * 32, SLD, q, c16);
        storeC16<2, true>(acc1, StS[1] + wv * 32, SLD, q, c16);
    }
    __syncthreads();

    // ---- phase 1: invc + rsA (VALU) + embed2 (MFMA) ----
    if (tid < 20) {
        int g = tid / 10, j = tid - g * 10;
        float c1 = 0.f;
#pragma unroll
        for (int i = 0; i < 10; ++i) c1 += (AsS[g][i * 10 + j] > 0.f) ? 1.f : 0.f;
        invc1S[g][j] = 1.f / fmaxf(c1, 1.f);
        invc0S[g][j] = 1.f / fmaxf(10.f - c1, 1.f);
        float r = 0.f;
#pragma unroll
        for (int k = 0; k < 10; ++k) r += fabsf(AsS[g][j * 10 + k]);
        rsAS[g][j] = r;
    }
    {   // embed2: H = H1@We2 + be2 -> Hf (fp32)
        f32x4 acc0[2], acc1[2];
        initC<2>(acc0, be2 + wv * 32, c16);
        initC<2>(acc1, be2 + wv * 32, c16);
        mm2_a16<4, 2>(ws + WS_WE2 + (size_t)wv * 4096, StS[0], StS[1], SLD, mrow, q, l, acc0, acc1);
#pragma unroll
        for (int j = 0; j < 2; ++j)
#pragma unroll
            for (int i = 0; i < 4; ++i) {
                int r = q * 4 + i;
                if (r < 10) {
                    HfS[0][r * HLD + wv * 32 + j * 16 + c16] = acc0[j][i];
                    HfS[1][r * HLD + wv * 32 + j * 16 + c16] = acc1[j][i];
                }
            }
    }
    __syncthreads();

    // ---- phase 2: coefficient matrices (layer-invariant):
    //   agg[i] = sum_k C0[i,k]·HW0[k] + C1[i,k]·HW1[k] + |A[i,k]|·HWr[k] + rsA[i]·b
    if (tid < 200) {
        int g = tid / 100, e = tid - g * 100;
        int i = e / 10, k = e - i * 10;
        const float* As = AsS[g];
        float c0 = 0.f, c1 = 0.f;
#pragma unroll
        for (int j = 0; j < 10; ++j) {
            float aij = fabsf(As[i * 10 + j]);
            if (As[k * 10 + j] > 0.f) c1 += aij * invc1S[g][j];
            else                      c0 += aij * invc0S[g][j];
        }
        C0S[g][e] = c0; C1S[g][e] = c1;
    }
    __syncthreads();

    const v2f lg2 = *(const v2f*)(ln_g + 2 * l);
    const v2f lb2 = *(const v2f*)(ln_b + 2 * l);

    // ---- layers ----
    for (int ll = 0; ll < L_; ++ll) {
        // RGCN matmuls DE-FUSED into 3 passes (16 acc VGPRs each, not 48):
        // HW0 -> St[0:128], HW1 -> St[128:256], HWr -> St[256:384]
#pragma unroll 1
        for (int m = 0; m < 3; ++m) {
            const short* Wf;
            if      (m == 0) Wf = ws + WS_RGW + (size_t)(ll * 2 + 0) * 16384 + (size_t)wv * 4096;
            else if (m == 1) Wf = ws + WS_RGW + (size_t)(ll * 2 + 1) * 16384 + (size_t)wv * 4096;
            else             Wf = ws + WS_RGR + (size_t)ll * 16384 + (size_t)wv * 4096;
            f32x4 acc0[2], acc1[2];
#pragma unroll
            for (int j = 0; j < 2; ++j) {
                acc0[j] = (f32x4){0.f, 0.f, 0.f, 0.f};
                acc1[j] = (f32x4){0.f, 0.f, 0.f, 0.f};
            }
            mm2_a32<4, 2>(Wf, HfS[0], HfS[1], HLD, mrow, q, l, acc0, acc1);
            storeC16<2, false>(acc0, StS[0] + m * 128 + wv * 32, SLD, q, c16);
            storeC16<2, false>(acc1, StS[1] + m * 128 + wv * 32, SLD, q, c16);
        }
        __syncthreads();
        // combine + LN + relu (VALU): wave wv owns tasks t = wv+4s, t=(g,i)
        {
            v2f rb2 = *(const v2f*)(rgcn_b + ll * D_ + 2 * l);
            short2 lnout[5];
#pragma unroll
            for (int s = 0; s < 5; ++s) {
                int t = wv + 4 * s;            // 0..19
                int g = (t >= 10) ? 1 : 0, i = t - g * 10;
                const short* St = StS[g];
                const float* C0 = C0S[g] + i * 10;
                const float* C1 = C1S[g] + i * 10;
                const float* As = AsS[g] + i * 10;
                v2f ag = splat2(rsAS[g][i]) * rb2;
#pragma unroll
                for (int j = 0; j < 10; ++j) {
                    short2 h0 = *(const short2*)(St + j * SLD + 2 * l);
                    short2 h1 = *(const short2*)(St + j * SLD + 128 + 2 * l);
                    short2 hr = *(const short2*)(St + j * SLD + 256 + 2 * l);
                    v2f v0; v0.x = hs2f(h0.x); v0.y = hs2f(h0.y);
                    v2f v1; v1.x = hs2f(h1.x); v1.y = hs2f(h1.y);
                    v2f vr; vr.x = hs2f(hr.x); vr.y = hs2f(hr.y);
                    ag = fma2(splat2(C0[j]), v0, ag);
                    ag = fma2(splat2(C1[j]), v1, ag);
                    ag = fma2(splat2(fabsf(As[j])), vr, ag);
                }
                float sm = ag.x + ag.y;
                float ss = fmaf(ag.x, ag.x, ag.y * ag.y);
#pragma unroll
                for (int off = 32; off > 0; off >>= 1) {
                    sm += __shfl_xor(sm, off);
                    ss += __shfl_xor(ss, off);
                }
                float mu   = sm * (1.f / 128.f);
                float var  = ss * (1.f / 128.f) - mu * mu;
                float rstd = rsqrtf(var + EPS_);
                v2f v = fma2((ag - splat2(mu)) * splat2(rstd), lg2, lb2);
                lnout[s].x = f2hs(fmaxf(v.x, 0.f));
                lnout[s].y = f2hs(fmaxf(v.y, 0.f));
            }
            __syncthreads();                   // all HW* reads done
#pragma unroll
            for (int s = 0; s < 5; ++s) {
                int t = wv + 4 * s;
                int g = (t >= 10) ? 1 : 0, i = t - g * 10;
                *(short2*)(StS[g] + i * SLD + 2 * l) = lnout[s];   // LNout -> cols 0:128
            }
        }
        __syncthreads();
        // MLP1: relu(LNout @ l1w + l1b): reads St[0:128], writes St[128:256]
        {
            f32x4 acc0[2], acc1[2];
            initC<2>(acc0, l1b + ll * D_ + wv * 32, c16);
            initC<2>(acc1, l1b + ll * D_ + wv * 32, c16);
            mm2_a16<4, 2>(ws + WS_L1 + (size_t)ll * 16384 + (size_t)wv * 4096,
                          StS[0], StS[1], SLD, mrow, q, l, acc0, acc1);
            storeC16<2, true>(acc0, StS[0] + 128 + wv * 32, SLD, q, c16);
            storeC16<2, true>(acc1, StS[1] + 128 + wv * 32, SLD, q, c16);
        }
        __syncthreads();
        // MLP2: hidden @ l2w + l2b: reads St[128:256], Hf += result
        {
            f32x4 acc0[2], acc1[2];
            initC<2>(acc0, l2b + ll * D_ + wv * 32, c16);
            initC<2>(acc1, l2b + ll * D_ + wv * 32, c16);
            mm2_a16<4, 2>(ws + WS_L2 + (size_t)ll * 16384 + (size_t)wv * 4096,
                          StS[0] + 128, StS[1] + 128, SLD, mrow, q, l, acc0, acc1);
#pragma unroll
            for (int j = 0; j < 2; ++j)
#pragma unroll
                for (int i = 0; i < 4; ++i) {
                    int r = q * 4 + i;
                    if (r < 10) {
                        HfS[0][r * HLD + wv * 32 + j * 16 + c16] += acc0[j][i];
                        HfS[1][r * HLD + wv * 32 + j * 16 + c16] += acc1[j][i];
                    }
                }
        }
        __syncthreads();
    }

    // ---- phi1: relu(H @ p1w + p1b) -> St[g][0:256]; 2 passes of NTP=2 ----
#pragma unroll 1
    for (int half = 0; half < 2; ++half) {
        const int nt0 = 4 * wv + 2 * half;
        f32x4 acc0[2], acc1[2];
        initC<2>(acc0, p1b + nt0 * 16, c16);
        initC<2>(acc1, p1b + nt0 * 16, c16);
        mm2_a32<4, 2>(ws + WS_P1 + (size_t)nt0 * 2048, HfS[0], HfS[1], HLD, mrow, q, l, acc0, acc1);
        storeC16<2, true>(acc0, StS[0] + nt0 * 16, SLD, q, c16);
        storeC16<2, true>(acc1, StS[1] + nt0 * 16, SLD, q, c16);
    }
    __syncthreads();
    // ---- phi2 + masked column sums -> RhoS[g]; 2 passes of NTP=2 ----
#pragma unroll 1
    for (int half = 0; half < 2; ++half) {
        const int nt0 = 4 * wv + 2 * half;
        f32x4 acc0[2], acc1[2];
        initC<2>(acc0, p2b + nt0 * 16, c16);
        initC<2>(acc1, p2b + nt0 * 16, c16);
        mm2_a16<8, 2>(ws + WS_P2 + (size_t)nt0 * 4096, StS[0], StS[1], SLD, mrow, q, l, acc0, acc1);
        // static-bound epilogue: called with acc0 then acc1 (no runtime select)
        auto sumepi = [&](const f32x4* acc, int g) {
            float hm0 = hmfS[g][q * 4 + 0], hm1 = hmfS[g][q * 4 + 1];
            float hm2 = hmfS[g][q * 4 + 2], hm3 = hmfS[g][q * 4 + 3];
            float aw0 = awfS[g][q * 4 + 0], aw1 = awfS[g][q * 4 + 1];
            float aw2 = awfS[g][q * 4 + 2], aw3 = awfS[g][q * 4 + 3];
#pragma unroll
            for (int t = 0; t < 2; ++t) {
                float v0 = fmaxf(acc[t][0], 0.f), v1 = fmaxf(acc[t][1], 0.f);
                float v2 = fmaxf(acc[t][2], 0.f), v3 = fmaxf(acc[t][3], 0.f);
                float hp = hm0 * v0 + hm1 * v1 + hm2 * v2 + hm3 * v3;
                float ap = aw0 * v0 + aw1 * v1 + aw2 * v2 + aw3 * v3;
                hp += __shfl_xor(hp, 16); hp += __shfl_xor(hp, 32);
                ap += __shfl_xor(ap, 16); ap += __shfl_xor(ap, 32);
                if (l < 16) {
                    RhoS[g][(nt0 + t) * 16 + l]       = f2hs(hp);
                    RhoS[g][256 + (nt0 + t) * 16 + l] = f2hs(ap);
                }
            }
        };
        sumepi(acc0, 0);
        sumepi(acc1, 1);
    }
    __syncthreads();
    // ---- rho: relu([hs;aws] @ r1w + r1b) @ r2w; antisym difference ----
    {
        f32x4 acc0[2], acc1[2];
        initC<2>(acc0, r1b + wv * 32, c16);
        initC<2>(acc1, r1b + wv * 32, c16);
        const int rr = (c16 < 2) ? c16 : 0;
        mm2_a16<8, 2>(ws + WS_R1 + (size_t)wv * 8192, RhoS[0], RhoS[1], 256, rr, q, l, acc0, acc1);
        auto rhoepi = [&](const f32x4* acc, int g) {
            float d = 0.f;
            if (q == 0) {
#pragma unroll
                for (int t = 0; t < 2; ++t) {
                    float vh = fmaxf(acc[t][0], 0.f);
                    float va = fmaxf(acc[t][1], 0.f);
                    d = fmaf(vh - va, r2w[(wv * 2 + t) * 16 + c16], d);
                }
            }
#pragma unroll
            for (int off = 32; off > 0; off >>= 1) d += __shfl_xor(d, off);
            if (l == 0) dS[g * 4 + wv] = d;
        };
        rhoepi(acc0, 0);
        rhoepi(acc1, 1);
    }
    __syncthreads();
    if (tid < 2)
        out[2 * b + tid] = 0.5f + 0.5f * tanhf(dS[tid * 4] + dS[tid * 4 + 1] +
                                               dS[tid * 4 + 2] + dS[tid * 4 + 3]);
}

extern "C" void kernel_launch(void* const* d_in, const int* in_sizes, int n_in,
                              void* d_out, int out_size, void* d_ws, size_t ws_size,
                              hipStream_t stream) {
    const float* A         = (const float*)d_in[0];
    const float* X         = (const float*)d_in[1];
    const int*   home_mask = (const int*)  d_in[2];
    const float* We1       = (const float*)d_in[3];
    const float* be1       = (const float*)d_in[4];
    const float* We2       = (const float*)d_in[5];
    const float* be2       = (const float*)d_in[6];
    const float* rgcn_w    = (const float*)d_in[7];
    const float* rgcn_root = (const float*)d_in[8];
    const float* rgcn_b    = (const float*)d_in[9];
    const float* l1w       = (const float*)d_in[10];
    const float* l1b       = (const float*)d_in[11];
    const float* l2w       = (const float*)d_in[12];
    const float* l2b       = (const float*)d_in[13];
    const float* ln_g      = (const float*)d_in[14];
    const float* ln_b      = (const float*)d_in[15];
    const float* p1w       = (const float*)d_in[16];
    const float* p1b       = (const float*)d_in[17];
    const float* p2w       = (const float*)d_in[18];
    const float* p2b       = (const float*)d_in[19];
    const float* r1w       = (const float*)d_in[20];
    const float* r1b       = (const float*)d_in[21];
    const float* r2w       = (const float*)d_in[22];

    short* ws = (short*)d_ws;

    prep_weights<<<776, 64, 0, stream>>>(We1, We2, rgcn_w, rgcn_root,
                                         l1w, l2w, p1w, p2w, r1w, ws);
    gcn_main<<<B_ / 2, 256, 0, stream>>>(A, X, home_mask, be1, be2, rgcn_b,
                                         l1b, l2b, ln_g, ln_b, p1b, p2b,
                                         r1b, r2w, ws, (float*)d_out);
}